// Round 1
// baseline (842.289 us; speedup 1.0000x reference)
//
#include <hip/hip_runtime.h>

// MaxUnpooling2D: out[b, y, x, c] += updates[b, h, w, c]
// where y = mask/(OW*C), x = (mask/C)%OW, and channel = c (NOT mask%C).
// With C=64, OW=256: per-batch out offset = (mask & ~63) | c.
// B=16, H=W=128, C=64, OH=OW=256.

constexpr int B = 16, H = 128, W = 128, C = 64;
constexpr int OH = 256, OW = 256;
constexpr int N = B * H * W * C;            // 16,777,216 inputs
constexpr int OUT_N = B * OH * OW * C;      // 67,108,864 outputs
constexpr int IN_BATCH_SHIFT = 20;          // H*W*C = 2^20
constexpr int OUT_BATCH_SHIFT = 22;         // OH*OW*C = 2^22

__global__ __launch_bounds__(256) void unpool_scatter_kernel(
    const float4* __restrict__ upd, const int4* __restrict__ mask,
    float* __restrict__ out, int nvec) {
    int i = blockIdx.x * blockDim.x + threadIdx.x;
    if (i >= nvec) return;

    float4 u = upd[i];
    int4 m = mask[i];

    int flat = i << 2;                      // first scalar index of this vec4
    int b = flat >> IN_BATCH_SHIFT;
    float* obase = out + ((long)b << OUT_BATCH_SHIFT);
    int c0 = flat & 63;                     // vec4 never straddles C=64 boundary

    atomicAdd(obase + ((m.x & ~63) | (c0 + 0)), u.x);
    atomicAdd(obase + ((m.y & ~63) | (c0 + 1)), u.y);
    atomicAdd(obase + ((m.z & ~63) | (c0 + 2)), u.z);
    atomicAdd(obase + ((m.w & ~63) | (c0 + 3)), u.w);
}

extern "C" void kernel_launch(void* const* d_in, const int* in_sizes, int n_in,
                              void* d_out, int out_size, void* d_ws, size_t ws_size,
                              hipStream_t stream) {
    const float4* upd = (const float4*)d_in[0];
    const int4* mask = (const int4*)d_in[1];
    float* out = (float*)d_out;

    // Output must be zeroed every call (harness poisons once, never re-poisons).
    hipMemsetAsync(d_out, 0, (size_t)OUT_N * sizeof(float), stream);

    int nvec = N / 4;                       // 4,194,304
    int block = 256;
    int grid = (nvec + block - 1) / block;  // 16,384 blocks
    unpool_scatter_kernel<<<grid, block, 0, stream>>>(upd, mask, out, nvec);
}